// Round 7
// baseline (360.334 us; speedup 1.0000x reference)
//
#include <hip/hip_runtime.h>

// iRPE contextual/transposed PRODUCT:
//   lt[b,h,i,k] = sum_d x[b,h,i,d] * W[h,d,k]   (K=49 GEMV per row)
//   out[b,h,i,j] = lt[b,h,i, bucket[i,j]]        (the 256 MB write)
//
// Round-7: r5's winning store structure (NT stores, plane-strided phase C,
// i-mod-8 CU spread) with two changes:
//  (a) phase-B LDS reads vectorized to float4 (ds_read_b128): 64 -> 16
//      LDS instrs per iteration, halving LDS-pipe pressure that throttled
//      the dependent store stream.
//  (b) grid split 2048 -> 4096 blocks (16 planes/block, 7.1 KB LDS, still
//      8 blocks/CU): TWO block generations, so gen-2's load/GEMV phases
//      overlap gen-1's store tail instead of serializing globally.

constexpr int cL = 1024;
constexpr int cD = 64;
constexpr int cK = 49;
constexpr int BG = 16;   // bh planes per block

typedef float vf4 __attribute__((ext_vector_type(4)));

__global__ __launch_bounds__(256, 8) void irpe_fused(
    const float* __restrict__ x,       // (B,H,L,D) = (bh, i, d)
    const float* __restrict__ W,       // (H,D,K)
    const int*   __restrict__ bucket,  // (L,L), values in [0,49)
    float*       __restrict__ out)     // (B,H,L,L)
{
    __shared__ float xs[BG][cD];       // 4 KB
    __shared__ float lts[BG * cK];     // 3.06 KB

    // Bijective gid -> (i, quarter) map, 12 bits:
    //   quarter = bits[1:0]  (which 16-plane group)
    //   i_hi    = bits[11] * 64 + bits[7:2]
    //   i_lo    = bits[10:8]
    // Round-robin CU c holds gids c+256k -> i_lo = 0..7 (full mod-8 channel
    // spread, r5's win) with i_hi/quarter fixed -> 8 consecutive i rows.
    const int gid     = blockIdx.x;
    const int quarter = gid & 3;
    const int i_lo    = (gid >> 8) & 7;
    const int i_hi    = ((gid >> 11) & 1) * 64 + ((gid >> 2) & 63);
    const int i       = i_hi * 8 + i_lo;
    const int bh0     = quarter * BG;
    const int tid     = threadIdx.x;

    // ---- Phase A: stage 16 x rows (one float4 per thread, coalesced) ----
    {
        const int lh = tid >> 4;       // 0..15
        const int d4 = tid & 15;       // 0..15
        ((vf4*)xs[lh])[d4] = __builtin_nontemporal_load(
            &((const vf4*)x)[((size_t)(bh0 + lh) * cL + i) * (cD / 4) + d4]);
    }
    // bucket row i -> registers (shared by the 4 quarter-blocks via L2)
    const int4 bk = ((const int4*)(bucket + (size_t)i * cL))[tid];
    __syncthreads();

    // ---- Phase B: lts[lh*49+k] = sum_d xs[lh][d] * W[h,d,k] ----
    // xs read as float4 (ds_read_b128); W loads coalesced across lanes
    // (consecutive lanes -> consecutive k), W L2-resident (100 KB).
    for (int p = tid; p < BG * cK; p += 256) {
        const int lh = p / cK;
        const int k  = p - lh * cK;
        const int h  = lh & 7;         // (bh0+lh)&7 == lh&7 (bh0 % 16 == 0)
        const float* wp = W + (size_t)h * cD * cK + k;
        const vf4* xr4 = (const vf4*)xs[lh];
        float acc = 0.0f;
        #pragma unroll
        for (int d4 = 0; d4 < cD / 4; ++d4) {
            const vf4 xv = xr4[d4];
            acc = fmaf(xv.x, wp[(d4 * 4 + 0) * cK], acc);
            acc = fmaf(xv.y, wp[(d4 * 4 + 1) * cK], acc);
            acc = fmaf(xv.z, wp[(d4 * 4 + 2) * cK], acc);
            acc = fmaf(xv.w, wp[(d4 * 4 + 3) * cK], acc);
        }
        lts[p] = acc;
    }
    __syncthreads();

    // ---- Phase C: gather + 16 x 4 KB NT stores, plane-strided (r5 walk) ----
    vf4* obase = (vf4*)out + ((size_t)bh0 * cL + i) * (cL / 4);
    #pragma unroll 4
    for (int lh = 0; lh < BG; ++lh) {
        const float* lrow = lts + lh * cK;
        vf4 o;
        o.x = lrow[bk.x];
        o.y = lrow[bk.y];
        o.z = lrow[bk.z];
        o.w = lrow[bk.w];
        __builtin_nontemporal_store(o, &obase[(size_t)lh * cL * (cL / 4) + tid]);
    }
}

extern "C" void kernel_launch(void* const* d_in, const int* in_sizes, int n_in,
                              void* d_out, int out_size, void* d_ws, size_t ws_size,
                              hipStream_t stream) {
    const float* x      = (const float*)d_in[0];   // (8,8,1024,64) fp32
    const float* W      = (const float*)d_in[1];   // (8,64,49) fp32
    const int*   bucket = (const int*)d_in[2];     // (1024,1024) int32
    float*       out    = (float*)d_out;           // (8,8,1024,1024) fp32

    const int grid = cL * 4;                        // 4096 blocks, 2 generations
    irpe_fused<<<grid, 256, 0, stream>>>(x, W, bucket, out);
}

// Round 8
// 331.861 us; speedup vs baseline: 1.0858x; 1.0858x over previous
//
#include <hip/hip_runtime.h>

// iRPE contextual/transposed PRODUCT:
//   lt[b,h,i,k] = sum_d x[b,h,i,d] * W[h,d,k]   (K=49 GEMV per row)
//   out[b,h,i,j] = lt[b,h,i, bucket[i,j]]        (the 256 MB write)
//
// Round-8: kill the GEMV's operand-delivery LDS cost (was ~25K wave-LDS
// instrs/CU = ~60 us of LDS-pipe, the hidden co-bottleneck). Block = one i
// x all 64 bh, 512 threads = 8 waves. Wave w owns h=w: its W slice
// W[w][d][k=lane] sits in 64 VGPRs (loaded once); the x row address is
// wave-uniform so x comes via s_load into SGPRs. The 64-FMA GEMV then uses
// ZERO LDS and ZERO per-FMA VMEM. lt round-trips through a 256-B
// wave-private LDS scratch (wave-synchronous, no barriers), then r5's
// proven gather + NT float4 store walk.

constexpr int cL = 1024;
constexpr int cD = 64;
constexpr int cK = 49;

typedef float vf4 __attribute__((ext_vector_type(4)));

__global__ __launch_bounds__(512, 4) void irpe_fused(
    const float* __restrict__ x,       // (B,H,L,D) = (bh, i, d)
    const float* __restrict__ W,       // (H,D,K)
    const int*   __restrict__ bucket,  // (L,L), values in [0,49)
    float*       __restrict__ out)     // (B,H,L,L)
{
    __shared__ float sc[8][64];        // per-wave lt scratch, 2 KB

    const int gid  = blockIdx.x;
    // bijective gid -> i; consecutive gids (-> different CUs) get i 4 apart,
    // generations shift i by 1 -> mixed channel residues + L2 x-locality.
    const int i    = ((gid & 255) << 2) | (gid >> 8);   // 0..1023
    const int tid  = threadIdx.x;
    const int lane = tid & 63;
    const int w    = tid >> 6;         // wave id == h

    // ---- W slice -> 64 VGPRs: wr[d] = W[w][d][min(lane,48)] ----
    // Per d: lanes read 49 consecutive dwords (196 B) -> ~4 lines, L2-hot.
    const int kc = lane < cK ? lane : (cK - 1);
    const float* wb = W + (size_t)w * cD * cK + kc;
    float wr[cD];
    #pragma unroll
    for (int d = 0; d < cD; ++d)
        wr[d] = wb[(size_t)d * cK];

    const int4* brow = (const int4*)(bucket + (size_t)i * cL);  // 256 int4

    // ---- plane loop: wave w handles bh = 8q + w (h == w for all) ----
    for (int q = 0; q < 8; ++q) {
        const int bh = q * 8 + w;

        // x row: wave-uniform address -> scalar loads (SGPRs), zero LDS
        const float* xr = x + ((size_t)bh * cL + i) * cD;
        float acc = 0.0f;
        #pragma unroll
        for (int d = 0; d < cD; ++d)
            acc = fmaf(xr[d], wr[d], acc);

        // lt (lane k) -> wave-private scratch; wave-synchronous, no barrier
        sc[w][lane] = acc;

        // gather + 4 KB of NT float4 stores for this (bh, i) row
        vf4* orow = (vf4*)(out + ((size_t)bh * cL + i) * cL);
        #pragma unroll
        for (int t = 0; t < 4; ++t) {
            const int4 bk = brow[t * 64 + lane];
            const float* s = sc[w];
            vf4 o;
            o.x = s[bk.x];
            o.y = s[bk.y];
            o.z = s[bk.z];
            o.w = s[bk.w];
            __builtin_nontemporal_store(o, &orow[t * 64 + lane]);
        }
    }
}

extern "C" void kernel_launch(void* const* d_in, const int* in_sizes, int n_in,
                              void* d_out, int out_size, void* d_ws, size_t ws_size,
                              hipStream_t stream) {
    const float* x      = (const float*)d_in[0];   // (8,8,1024,64) fp32
    const float* W      = (const float*)d_in[1];   // (8,64,49) fp32
    const int*   bucket = (const int*)d_in[2];     // (1024,1024) int32
    float*       out    = (float*)d_out;           // (8,8,1024,1024) fp32

    irpe_fused<<<cL, 512, 0, stream>>>(x, W, bucket, out);   // 1024 blocks
}